// Round 2
// baseline (4119.860 us; speedup 1.0000x reference)
//
#include <hip/hip_runtime.h>

// TrajectoryTransformer fused bf16-MFMA implementation for MI355X (gfx950).
// B=256 T=100 IN=6 D=1024 H=8 HD=128 L=4 OUT=256.
// Mask in reference is constant along softmax axis -> provable no-op -> dropped.
// R2: workspace cut 448->362 MiB (per-layer weight cvt; wot aliases ctxb) —
//     R1 abort attributed to d_ws overflow (only unchecked OOB candidate).

#define B_    256
#define T_    100
#define D_    1024
#define H_    8
#define HD_   128
#define L_    4
#define BT_   25600          // B*T
#define DQ_   3072           // 3*D
#define OUT_  256
#define KFIN_ 102400         // T*D
#define SCALE_ 0.08838834764831845f  // 1/sqrt(128)

typedef unsigned short ushort_t;
typedef __attribute__((ext_vector_type(8))) short bf16x8;   // 8 bf16 (4 VGPRs)
typedef __attribute__((ext_vector_type(4))) float f32x4;    // MFMA C/D

__device__ inline ushort_t f2bf(float f) {   // RNE fp32 -> bf16
  unsigned u = __float_as_uint(f);
  u += 0x7FFFu + ((u >> 16) & 1u);
  return (ushort_t)(u >> 16);
}

// async global->LDS, 16B per lane; LDS dest is wave-uniform base + lane*16
__device__ inline void gld16(const void* g, void* l) {
  __builtin_amdgcn_global_load_lds(
      (__attribute__((address_space(1))) unsigned int*)(size_t)g,
      (__attribute__((address_space(3))) unsigned int*)l, 16, 0, 0);
}

// XOR swizzle: chunk index for (row, k-group q) in a [128][32] bf16 tile.
// Gives ~2-way max LDS bank aliasing on ds_read_b128 (free per m136).
__device__ inline int swz(int r, int q) {
  return r * 4 + (q ^ (r & 3) ^ ((r >> 2) & 3));
}

// ---------------------------------------------------------------------------
// C[m,n] = sum_k A[m,k]*Bw[n,k] (+bias, relu, resid, bf16/f32/atomic out)
// A:[M,K] bf16 row-major, Bw:[N,K] bf16 row-major. 128x128 tile, BK=32.
// grid: (N/128, M/128, ksplit); each z-block covers ksteps*32 of K.
// ---------------------------------------------------------------------------
template<int RELU, int RESID, int OBF, int OF32, int ATOM>
__global__ __launch_bounds__(256)
void gemm_nt(const ushort_t* __restrict__ A, const ushort_t* __restrict__ Bw,
             const float* __restrict__ bias,
             ushort_t* outb, float* outf, const float* resid,
             int M, int N, int K, int ksteps)
{
  __shared__ ushort_t lsA[4096];
  __shared__ ushort_t lsB[4096];
  const int tid = threadIdx.x, lane = tid & 63, wave = tid >> 6;
  const int fr = lane & 15, q = lane >> 4;
  const int m0 = blockIdx.y * 128, n0 = blockIdx.x * 128;
  const int wm = (wave >> 1) * 64, wn = (wave & 1) * 64;
  const int kbase = blockIdx.z * ksteps * 32;

  const ushort_t* Ab = A + (size_t)m0 * K + kbase;
  const ushort_t* Bb = Bw + (size_t)n0 * K + kbase;

  // staging geometry: 512 chunks of 16B per tile; 8 wave-insts of 64 lanes
  const int c0 = (wave * 2 + 0) * 64 + lane;
  const int c1 = (wave * 2 + 1) * 64 + lane;
  const int r0 = c0 >> 2, kg0 = (c0 & 3) ^ (r0 & 3) ^ ((r0 >> 2) & 3);
  const int r1 = c1 >> 2, kg1 = (c1 & 3) ^ (r1 & 3) ^ ((r1 >> 2) & 3);
  const ushort_t* ga0 = Ab + (size_t)r0 * K + kg0 * 8;
  const ushort_t* ga1 = Ab + (size_t)r1 * K + kg1 * 8;
  const ushort_t* gb0 = Bb + (size_t)r0 * K + kg0 * 8;
  const ushort_t* gb1 = Bb + (size_t)r1 * K + kg1 * 8;
  ushort_t* la0 = lsA + (wave * 2 + 0) * 512;
  ushort_t* la1 = lsA + (wave * 2 + 1) * 512;
  ushort_t* lb0 = lsB + (wave * 2 + 0) * 512;
  ushort_t* lb1 = lsB + (wave * 2 + 1) * 512;

  f32x4 acc[4][4];
  #pragma unroll
  for (int i = 0; i < 4; i++)
    #pragma unroll
    for (int j = 0; j < 4; j++) acc[i][j] = 0.f;

  int aoff[4], boff[4];
  #pragma unroll
  for (int t = 0; t < 4; t++) {
    aoff[t] = swz(wm + t * 16 + fr, q) * 8;
    boff[t] = swz(wn + t * 16 + fr, q) * 8;
  }

  for (int ks = 0; ks < ksteps; ks++) {
    __syncthreads();
    gld16(ga0 + ks * 32, la0);
    gld16(ga1 + ks * 32, la1);
    gld16(gb0 + ks * 32, lb0);
    gld16(gb1 + ks * 32, lb1);
    __syncthreads();
    bf16x8 af[4], bfv[4];
    #pragma unroll
    for (int t = 0; t < 4; t++) {
      af[t]  = *(const bf16x8*)(lsA + aoff[t]);
      bfv[t] = *(const bf16x8*)(lsB + boff[t]);
    }
    #pragma unroll
    for (int i = 0; i < 4; i++)
      #pragma unroll
      for (int j = 0; j < 4; j++)
        acc[i][j] = __builtin_amdgcn_mfma_f32_16x16x32_bf16(af[i], bfv[j], acc[i][j], 0, 0, 0);
  }

  // epilogue: C/D layout col=lane&15, row=(lane>>4)*4+reg (m89/m91-verified)
  #pragma unroll
  for (int i = 0; i < 4; i++) {
    const int rb = m0 + wm + i * 16 + q * 4;
    #pragma unroll
    for (int j = 0; j < 4; j++) {
      const int col = n0 + wn + j * 16 + fr;
      const float bv = bias ? bias[col] : 0.f;
      #pragma unroll
      for (int rr = 0; rr < 4; rr++) {
        float v = acc[i][j][rr] + bv;
        if (RELU) v = fmaxf(v, 0.f);
        const size_t idx = (size_t)(rb + rr) * N + col;
        if (RESID) v += resid[idx];
        if (ATOM) { atomicAdd(&outf[idx], v); }
        else {
          if (OF32) outf[idx] = v;
          if (OBF)  outb[idx] = f2bf(v);
        }
      }
    }
  }
}

// ---------------------------------------------------------------------------
// Fused attention: one block per (head, batch). qkv:[BT,3072] bf16.
// S=Q*K^T*scale -> fp32 softmax (LDS) -> ctx=P*V, queries in 2 chunks of 64.
// ---------------------------------------------------------------------------
#define SST 116   // S row stride (floats): 16B-aligned rows
#define VST 120   // Vt row stride (bf16):  16B-aligned rows

__global__ __launch_bounds__(256)
void attn_kernel(const ushort_t* __restrict__ qkv, ushort_t* __restrict__ ctx)
{
  __shared__ float    S[64 * SST];     // 29696 B
  __shared__ ushort_t Vt[128 * VST];   // 30720 B  (total 60416 < 64K)
  const int tid = threadIdx.x, lane = tid & 63, wave = tid >> 6;
  const int fr = lane & 15, q = lane >> 4;
  const int hh = blockIdx.x, bb = blockIdx.y;
  const size_t base = (size_t)bb * T_ * DQ_;
  const ushort_t* Qb = qkv + base + hh * HD_;
  const ushort_t* Kb = qkv + base + D_ + hh * HD_;
  const ushort_t* Vb = qkv + base + 2 * D_ + hh * HD_;

  // V -> Vt transposed (Vt[d][key]); zero pad keys 100..119
  for (int e = tid; e < T_ * HD_; e += 256) {
    const int j = e >> 7, d = e & 127;
    Vt[d * VST + j] = Vb[(size_t)j * DQ_ + d];
  }
  for (int e = tid; e < 128 * 20; e += 256) {
    const int d = e / 20, j = e - d * 20;
    Vt[d * VST + 100 + j] = 0;
  }

  for (int c = 0; c < 2; c++) {
    __syncthreads();
    // phase 1: S rows [c*64, c*64+64). wave -> i-tile c*4+wave.
    const int it  = c * 4 + wave;
    const bool wlive = (it < 7);
    const int itc = wlive ? it : 6;
    const int qrow = min(itc * 16 + fr, T_ - 1);   // clamp pad rows (safe dup)
    f32x4 sacc[7];
    #pragma unroll
    for (int jt = 0; jt < 7; jt++) sacc[jt] = 0.f;
    #pragma unroll
    for (int ks = 0; ks < 4; ks++) {
      const int kk = ks * 32 + q * 8;
      const bf16x8 aq = *(const bf16x8*)(Qb + (size_t)qrow * DQ_ + kk);
      #pragma unroll
      for (int jt = 0; jt < 7; jt++) {
        const int kr = min(jt * 16 + fr, T_ - 1);
        const bf16x8 kb = *(const bf16x8*)(Kb + (size_t)kr * DQ_ + kk);
        sacc[jt] = __builtin_amdgcn_mfma_f32_16x16x32_bf16(aq, kb, sacc[jt], 0, 0, 0);
      }
    }
    if (wlive) {
      #pragma unroll
      for (int jt = 0; jt < 7; jt++) {
        const int colb = jt * 16 + fr;
        #pragma unroll
        for (int rr = 0; rr < 4; rr++)
          S[(wave * 16 + q * 4 + rr) * SST + colb] = sacc[jt][rr] * SCALE_;
      }
    }
    __syncthreads();
    // phase 2: softmax over keys<100 (mask is a softmax no-op); zero 100..111
    if (tid < 64) {
      float4* row = (float4*)&S[tid * SST];
      float m = -1e30f;
      for (int jj = 0; jj < 25; jj++) {
        const float4 v = row[jj];
        m = fmaxf(m, fmaxf(fmaxf(v.x, v.y), fmaxf(v.z, v.w)));
      }
      float s = 0.f;
      for (int jj = 0; jj < 25; jj++) {
        float4 v = row[jj];
        v.x = __expf(v.x - m); v.y = __expf(v.y - m);
        v.z = __expf(v.z - m); v.w = __expf(v.w - m);
        s += v.x + v.y + v.z + v.w;
        row[jj] = v;
      }
      const float inv = 1.f / s;
      for (int jj = 0; jj < 25; jj++) {
        float4 v = row[jj];
        v.x *= inv; v.y *= inv; v.z *= inv; v.w *= inv;
        row[jj] = v;
      }
      row[25] = (float4){0.f,0.f,0.f,0.f};
      row[26] = (float4){0.f,0.f,0.f,0.f};
      row[27] = (float4){0.f,0.f,0.f,0.f};
    }
    __syncthreads();
    // phase 3: ctx = P*V. K dim padded to 112; k>=112 lanes feed zeros.
    const int mtc = (c == 0) ? 4 : 3;
    f32x4 cacc[4][2];
    #pragma unroll
    for (int i = 0; i < 4; i++) { cacc[i][0] = 0.f; cacc[i][1] = 0.f; }
    #pragma unroll
    for (int ks = 0; ks < 4; ks++) {
      const int kk = ks * 32 + q * 8;
      const bool live = (ks < 3) || (q < 2);
      bf16x8 v0 = 0, v1 = 0;
      if (live) {
        v0 = *(const bf16x8*)&Vt[((wave * 2 + 0) * 16 + fr) * VST + kk];
        v1 = *(const bf16x8*)&Vt[((wave * 2 + 1) * 16 + fr) * VST + kk];
      }
      for (int mt = 0; mt < mtc; mt++) {
        bf16x8 a = 0;
        if (live) {
          const float* pr = &S[(mt * 16 + fr) * SST + kk];
          const float4 p0 = *(const float4*)pr;
          const float4 p1 = *(const float4*)(pr + 4);
          a[0] = (short)f2bf(p0.x); a[1] = (short)f2bf(p0.y);
          a[2] = (short)f2bf(p0.z); a[3] = (short)f2bf(p0.w);
          a[4] = (short)f2bf(p1.x); a[5] = (short)f2bf(p1.y);
          a[6] = (short)f2bf(p1.z); a[7] = (short)f2bf(p1.w);
        }
        cacc[mt][0] = __builtin_amdgcn_mfma_f32_16x16x32_bf16(a, v0, cacc[mt][0], 0, 0, 0);
        cacc[mt][1] = __builtin_amdgcn_mfma_f32_16x16x32_bf16(a, v1, cacc[mt][1], 0, 0, 0);
      }
    }
    for (int mt = 0; mt < mtc; mt++) {
      #pragma unroll
      for (int nn = 0; nn < 2; nn++) {
        const int col = hh * HD_ + (wave * 2 + nn) * 16 + fr;
        #pragma unroll
        for (int rr = 0; rr < 4; rr++) {
          const int r = c * 64 + mt * 16 + q * 4 + rr;
          if (r < T_)
            ctx[(size_t)(bb * T_ + r) * D_ + col] = f2bf(cacc[mt][nn][rr]);
        }
      }
    }
  }
}

// ---------------------------------------------------------------------------
// LayerNorm in-place on hf, also emits bf16 copy. One block per row.
// ---------------------------------------------------------------------------
__global__ __launch_bounds__(256)
void ln_kernel(float* hf, ushort_t* hbf,
               const float* __restrict__ g, const float* __restrict__ bta)
{
  const int row = blockIdx.x, tid = threadIdx.x;
  float* rp = hf + (size_t)row * D_;
  const int c4 = tid * 4;
  const float4 v = *(float4*)(rp + c4);
  float s  = v.x + v.y + v.z + v.w;
  float ss = v.x*v.x + v.y*v.y + v.z*v.z + v.w*v.w;
  #pragma unroll
  for (int o = 1; o < 64; o <<= 1) {
    s  += __shfl_xor(s, o);
    ss += __shfl_xor(ss, o);
  }
  __shared__ float red[8];
  const int lane = tid & 63, wave = tid >> 6;
  if (lane == 0) { red[wave] = s; red[4 + wave] = ss; }
  __syncthreads();
  s  = red[0] + red[1] + red[2] + red[3];
  ss = red[4] + red[5] + red[6] + red[7];
  const float mean = s * (1.f / D_);
  const float var  = ss * (1.f / D_) - mean * mean;
  const float rstd = rsqrtf(var + 1e-5f);
  const float4 gv = *(const float4*)(g + c4);
  const float4 bv = *(const float4*)(bta + c4);
  const float o0 = (v.x - mean) * rstd * gv.x + bv.x;
  const float o1 = (v.y - mean) * rstd * gv.y + bv.y;
  const float o2 = (v.z - mean) * rstd * gv.z + bv.z;
  const float o3 = (v.w - mean) * rstd * gv.w + bv.w;
  *(float4*)(rp + c4) = (float4){o0, o1, o2, o3};
  ushort4 ob = { f2bf(o0), f2bf(o1), f2bf(o2), f2bf(o3) };
  *(ushort4*)(hbf + (size_t)row * D_ + c4) = ob;
}

// ---------------------------------------------------------------------------
// Embedding: h = x@Wi + bi + PE(t,:). One block per token row.
// ---------------------------------------------------------------------------
__global__ __launch_bounds__(256)
void embed_kernel(const float* __restrict__ x, const float* __restrict__ Wi,
                  const float* __restrict__ bi, float* hf, ushort_t* hbf)
{
  const int row = blockIdx.x;
  const int t = row % T_;
  const int c = threadIdx.x * 4;
  float xv[6];
  #pragma unroll
  for (int i = 0; i < 6; i++) xv[i] = x[row * 6 + i];
  float o[4];
  #pragma unroll
  for (int u = 0; u < 4; u++) {
    const int d = c + u;
    float a = bi[d];
    #pragma unroll
    for (int i = 0; i < 6; i++) a += xv[i] * Wi[i * D_ + d];
    const int k = d >> 1;
    const float ang = (float)t * expf((float)k * -0.017988946039015984f); // -ln(1e4)/512
    a += (d & 1) ? cosf(ang) : sinf(ang);
    o[u] = a;
  }
  *(float4*)(hf + (size_t)row * D_ + c) = (float4){o[0], o[1], o[2], o[3]};
  ushort4 ob = { f2bf(o[0]), f2bf(o[1]), f2bf(o[2]), f2bf(o[3]) };
  *(ushort4*)(hbf + (size_t)row * D_ + c) = ob;
}

__global__ void cvt_bf16(const float* __restrict__ s, ushort_t* __restrict__ d, int n)
{
  const int i = (blockIdx.x * 256 + threadIdx.x) * 4;
  if (i < n) {
    const float4 v = *(const float4*)(s + i);
    ushort4 o = { f2bf(v.x), f2bf(v.y), f2bf(v.z), f2bf(v.w) };
    *(ushort4*)(d + i) = o;
  }
}

// Wo [KFIN,256] fp32 -> Wot [256,KFIN] bf16 (so final GEMM is NT form)
__global__ __launch_bounds__(256)
void transpose_wo(const float* __restrict__ src, ushort_t* __restrict__ dst)
{
  __shared__ float tile[64][65];
  const int k0 = blockIdx.x * 64, n0 = blockIdx.y * 64;
  const int tc = threadIdx.x & 63, tr = threadIdx.x >> 6;
  #pragma unroll
  for (int i = 0; i < 16; i++) {
    const int r = i * 4 + tr;
    tile[r][tc] = src[(size_t)(k0 + r) * OUT_ + n0 + tc];
  }
  __syncthreads();
  #pragma unroll
  for (int i = 0; i < 16; i++) {
    const int n = i * 4 + tr;
    dst[(size_t)(n0 + n) * KFIN_ + k0 + tc] = f2bf(tile[tc][n]);
  }
}

__global__ void init_out(float* o, const float* __restrict__ bo)
{
  const int i = blockIdx.x * 256 + threadIdx.x;
  o[i] = bo[i & (OUT_ - 1)];
}

// ---------------------------------------------------------------------------
extern "C" void kernel_launch(void* const* d_in, const int* in_sizes, int n_in,
                              void* d_out, int out_size, void* d_ws, size_t ws_size,
                              hipStream_t stream)
{
  (void)in_sizes; (void)n_in; (void)out_size; (void)ws_size;
  const float* x     = (const float*)d_in[0];
  const float* Wi    = (const float*)d_in[1];
  const float* bi    = (const float*)d_in[2];
  const float* qkv_w = (const float*)d_in[3];
  const float* qkv_b = (const float*)d_in[4];
  const float* out_w = (const float*)d_in[5];
  const float* out_b = (const float*)d_in[6];
  const float* ff1_w = (const float*)d_in[7];
  const float* ff1_b = (const float*)d_in[8];
  const float* ff2_w = (const float*)d_in[9];
  const float* ff2_b = (const float*)d_in[10];
  const float* ln1_g = (const float*)d_in[11];
  const float* ln1_b = (const float*)d_in[12];
  const float* ln2_g = (const float*)d_in[13];
  const float* ln2_b = (const float*)d_in[14];
  const float* Wo    = (const float*)d_in[15];
  const float* bo    = (const float*)d_in[16];
  float* out = (float*)d_out;

  // workspace layout — 362 MiB peak (R2: per-layer weights, wot aliases ctxb)
  char* p = (char*)d_ws;
  float*    hf   = (float*)p;    p += (size_t)BT_ * D_ * 4;     // 104.9 MB
  ushort_t* hbf  = (ushort_t*)p; p += (size_t)BT_ * D_ * 2;     //  52.4 MB
  ushort_t* qkvb = (ushort_t*)p; p += (size_t)BT_ * DQ_ * 2;    // 157.3 MB
  ushort_t* ctxb = (ushort_t*)p; p += (size_t)BT_ * D_ * 2;     //  52.4 MB
  ushort_t* wlq  = (ushort_t*)p; p += (size_t)DQ_ * D_ * 2;     //   6.3 MB
  ushort_t* wlo  = (ushort_t*)p; p += (size_t)D_ * D_ * 2;      //   2.1 MB
  ushort_t* wl1  = (ushort_t*)p; p += (size_t)D_ * D_ * 2;      //   2.1 MB
  ushort_t* wl2  = (ushort_t*)p; p += (size_t)D_ * D_ * 2;      //   2.1 MB
  ushort_t* ffact = qkvb;   // alias: qkv dead once attention finishes
  ushort_t* wot   = ctxb;   // alias: ctx dead after last out-projection

  embed_kernel<<<dim3(BT_), 256, 0, stream>>>(x, Wi, bi, hf, hbf);

  for (int i = 0; i < L_; i++) {
    // layer weights -> bf16 (ws re-poisoned every call, must reconvert)
    cvt_bf16<<<dim3((DQ_*D_)/1024), 256, 0, stream>>>(qkv_w + (size_t)i*DQ_*D_, wlq, DQ_*D_);
    cvt_bf16<<<dim3((D_*D_)/1024), 256, 0, stream>>>(out_w + (size_t)i*D_*D_, wlo, D_*D_);
    cvt_bf16<<<dim3((D_*D_)/1024), 256, 0, stream>>>(ff1_w + (size_t)i*D_*D_, wl1, D_*D_);
    cvt_bf16<<<dim3((D_*D_)/1024), 256, 0, stream>>>(ff2_w + (size_t)i*D_*D_, wl2, D_*D_);

    // qkv = h @ qkv_w^T + b  -> bf16
    gemm_nt<0,0,1,0,0><<<dim3(DQ_/128, BT_/128, 1), 256, 0, stream>>>(
        hbf, wlq, qkv_b + i * DQ_,
        qkvb, nullptr, nullptr, BT_, DQ_, D_, D_ / 32);
    // fused attention per (head, batch)
    attn_kernel<<<dim3(H_, B_), 256, 0, stream>>>(qkvb, ctxb);
    // h += ctx @ out_w^T + b (fp32, in-place residual)
    gemm_nt<0,1,0,1,0><<<dim3(D_/128, BT_/128, 1), 256, 0, stream>>>(
        ctxb, wlo, out_b + i * D_,
        nullptr, hf, hf, BT_, D_, D_, D_ / 32);
    ln_kernel<<<dim3(BT_), 256, 0, stream>>>(hf, hbf, ln1_g + i * D_, ln1_b + i * D_);
    // ff = relu(h @ ff1^T + b) -> bf16
    gemm_nt<1,0,1,0,0><<<dim3(D_/128, BT_/128, 1), 256, 0, stream>>>(
        hbf, wl1, ff1_b + i * D_,
        ffact, nullptr, nullptr, BT_, D_, D_, D_ / 32);
    // h += ff @ ff2^T + b (fp32, in-place residual)
    gemm_nt<0,1,0,1,0><<<dim3(D_/128, BT_/128, 1), 256, 0, stream>>>(
        ffact, wl2, ff2_b + i * D_,
        nullptr, hf, hf, BT_, D_, D_, D_ / 32);
    ln_kernel<<<dim3(BT_), 256, 0, stream>>>(hf, hbf, ln2_g + i * D_, ln2_b + i * D_);
  }

  // final: out = h.reshape(256,102400) @ Wo + bo   (split-K + fp32 atomics)
  transpose_wo<<<dim3(KFIN_/64, OUT_/64), 256, 0, stream>>>(Wo, wot);
  init_out<<<dim3(OUT_ * OUT_ / 256), 256, 0, stream>>>(out, bo);
  gemm_nt<0,0,0,0,1><<<dim3(OUT_/128, OUT_/128, 64), 256, 0, stream>>>(
      hbf, wot, nullptr, nullptr, out, nullptr,
      OUT_, OUT_, KFIN_, KFIN_ / (64 * 32));
}

// Round 3
// 3416.940 us; speedup vs baseline: 1.2057x; 1.2057x over previous
//
#include <hip/hip_runtime.h>

// TrajectoryTransformer fused bf16-MFMA implementation for MI355X (gfx950).
// B=256 T=100 IN=6 D=1024 H=8 HD=128 L=4 OUT=256.
// Mask in reference is constant along softmax axis -> provable no-op -> dropped.
// R3: all-bf16 activation stream (no fp32 hf), upfront weight cvt (1 kernel),
//     LDS-repacked wide-store GEMM epilogue, split-K partials (no atomics).

#define B_    256
#define T_    100
#define D_    1024
#define H_    8
#define HD_   128
#define L_    4
#define BT_   25600          // B*T
#define DQ_   3072           // 3*D
#define OUT_  256
#define KFIN_ 102400         // T*D
#define KSPLIT_ 64
#define SCALE_ 0.08838834764831845f  // 1/sqrt(128)

typedef unsigned short ushort_t;
typedef __attribute__((ext_vector_type(8))) short bf16x8;   // 8 bf16 (4 VGPRs)
typedef __attribute__((ext_vector_type(4))) float f32x4;    // MFMA C/D

__device__ inline ushort_t f2bf(float f) {   // RNE fp32 -> bf16
  unsigned u = __float_as_uint(f);
  u += 0x7FFFu + ((u >> 16) & 1u);
  return (ushort_t)(u >> 16);
}
__device__ inline float bf2f(ushort_t u) {
  return __uint_as_float((unsigned)u << 16);
}

// async global->LDS, 16B per lane; LDS dest is wave-uniform base + lane*16
__device__ inline void gld16(const void* g, void* l) {
  __builtin_amdgcn_global_load_lds(
      (__attribute__((address_space(1))) unsigned int*)(size_t)g,
      (__attribute__((address_space(3))) unsigned int*)l, 16, 0, 0);
}

// XOR swizzle: chunk index for (row, k-group q) in a [128][32] bf16 tile.
__device__ inline int swz(int r, int q) {
  return r * 4 + (q ^ (r & 3) ^ ((r >> 2) & 3));
}

// ---------------------------------------------------------------------------
// C[m,n] = sum_k A[m,k]*Bw[n,k] (+bias, relu, bf16-resid; bf16 or f32-partial out)
// A:[M,K] bf16 row-major, Bw:[N,K] bf16 row-major. 128x128 tile, BK=32.
// grid: (N/128, M/128, ksplit). OF32 writes fp32 partial at z*M*N offset.
// ---------------------------------------------------------------------------
template<int RELU, int RESID, int OBF, int OF32>
__global__ __launch_bounds__(256)
void gemm_nt(const ushort_t* __restrict__ A, const ushort_t* __restrict__ Bw,
             const float* __restrict__ bias,
             ushort_t* outb, float* outf, const ushort_t* __restrict__ resid,
             int M, int N, int K, int ksteps)
{
  __shared__ ushort_t lds[8192];
  ushort_t* lsA = lds;
  ushort_t* lsB = lds + 4096;
  const int tid = threadIdx.x, lane = tid & 63, wave = tid >> 6;
  const int fr = lane & 15, q = lane >> 4;
  const int m0 = blockIdx.y * 128, n0 = blockIdx.x * 128;
  const int wm = (wave >> 1) * 64, wn = (wave & 1) * 64;
  const int kbase = blockIdx.z * ksteps * 32;

  const ushort_t* Ab = A + (size_t)m0 * K + kbase;
  const ushort_t* Bb = Bw + (size_t)n0 * K + kbase;

  // staging geometry: 512 chunks of 16B per tile; 8 wave-insts of 64 lanes
  const int c0 = (wave * 2 + 0) * 64 + lane;
  const int c1 = (wave * 2 + 1) * 64 + lane;
  const int r0 = c0 >> 2, kg0 = (c0 & 3) ^ (r0 & 3) ^ ((r0 >> 2) & 3);
  const int r1 = c1 >> 2, kg1 = (c1 & 3) ^ (r1 & 3) ^ ((r1 >> 2) & 3);
  const ushort_t* ga0 = Ab + (size_t)r0 * K + kg0 * 8;
  const ushort_t* ga1 = Ab + (size_t)r1 * K + kg1 * 8;
  const ushort_t* gb0 = Bb + (size_t)r0 * K + kg0 * 8;
  const ushort_t* gb1 = Bb + (size_t)r1 * K + kg1 * 8;
  ushort_t* la0 = lsA + (wave * 2 + 0) * 512;
  ushort_t* la1 = lsA + (wave * 2 + 1) * 512;
  ushort_t* lb0 = lsB + (wave * 2 + 0) * 512;
  ushort_t* lb1 = lsB + (wave * 2 + 1) * 512;

  f32x4 acc[4][4];
  #pragma unroll
  for (int i = 0; i < 4; i++)
    #pragma unroll
    for (int j = 0; j < 4; j++) acc[i][j] = 0.f;

  int aoff[4], boff[4];
  #pragma unroll
  for (int t = 0; t < 4; t++) {
    aoff[t] = swz(wm + t * 16 + fr, q) * 8;
    boff[t] = swz(wn + t * 16 + fr, q) * 8;
  }

  for (int ks = 0; ks < ksteps; ks++) {
    __syncthreads();
    gld16(ga0 + ks * 32, la0);
    gld16(ga1 + ks * 32, la1);
    gld16(gb0 + ks * 32, lb0);
    gld16(gb1 + ks * 32, lb1);
    __syncthreads();
    bf16x8 af[4], bfv[4];
    #pragma unroll
    for (int t = 0; t < 4; t++) {
      af[t]  = *(const bf16x8*)(lsA + aoff[t]);
      bfv[t] = *(const bf16x8*)(lsB + boff[t]);
    }
    #pragma unroll
    for (int i = 0; i < 4; i++)
      #pragma unroll
      for (int j = 0; j < 4; j++)
        acc[i][j] = __builtin_amdgcn_mfma_f32_16x16x32_bf16(af[i], bfv[j], acc[i][j], 0, 0, 0);
  }

  // C/D layout col=lane&15, row=(lane>>4)*4+reg (m89/m91-verified)
  if (OBF) {
    __syncthreads();                     // staging LDS now dead for all waves
    ushort_t* myl = lds + wave * 2048;   // private 4KB per wave
    const int rloc = lane >> 2, cg = lane & 3;
    #pragma unroll
    for (int hh = 0; hh < 2; hh++) {     // column halves (32 cols each)
      #pragma unroll
      for (int j2 = 0; j2 < 2; j2++) {
        const int j = 2 * hh + j2;
        const float bv = bias ? bias[n0 + wn + j * 16 + fr] : 0.f;
        #pragma unroll
        for (int i = 0; i < 4; i++) {
          #pragma unroll
          for (int rr = 0; rr < 4; rr++) {
            const int row = i * 16 + q * 4 + rr;
            const int col = j2 * 16 + fr;       // 0..31
            float v = acc[i][j][rr] + bv;
            if (RELU) v = fmaxf(v, 0.f);
            const int cgw = col >> 3, cwi = col & 7;
            myl[(row * 4 + (cgw ^ (row & 3) ^ ((row >> 2) & 3))) * 8 + cwi] = f2bf(v);
          }
        }
      }
      // read back 16B row-segments, wide coalesced stores (+bf16 resid)
      #pragma unroll
      for (int rb = 0; rb < 4; rb++) {
        const int row = rb * 16 + rloc;
        const int cgr = cg ^ (row & 3) ^ ((row >> 2) & 3);
        bf16x8 seg = *(const bf16x8*)&myl[(row * 4 + cgr) * 8];
        const size_t gaddr = (size_t)(m0 + wm + row) * N + (n0 + wn + hh * 32 + cg * 8);
        if (RESID) {
          const bf16x8 rv = *(const bf16x8*)&resid[gaddr];
          #pragma unroll
          for (int e = 0; e < 8; e++) {
            const float f = bf2f((ushort_t)seg[e]) + bf2f((ushort_t)rv[e]);
            seg[e] = (short)f2bf(f);
          }
        }
        *(bf16x8*)&outb[gaddr] = seg;
      }
    }
  }
  if (OF32) {  // fp32 split-K partial (final GEMM only; small output)
    float* po = outf + (size_t)blockIdx.z * M * N;
    #pragma unroll
    for (int i = 0; i < 4; i++) {
      const int rb = m0 + wm + i * 16 + q * 4;
      #pragma unroll
      for (int j = 0; j < 4; j++) {
        const int col = n0 + wn + j * 16 + fr;
        #pragma unroll
        for (int rr = 0; rr < 4; rr++)
          po[(size_t)(rb + rr) * N + col] = acc[i][j][rr];
      }
    }
  }
}

// ---------------------------------------------------------------------------
// Fused attention: one block per (head, batch). qkv:[BT,3072] bf16.
// ---------------------------------------------------------------------------
#define SST 116   // S row stride (floats)
#define VST 120   // Vt row stride (bf16)

__global__ __launch_bounds__(256)
void attn_kernel(const ushort_t* __restrict__ qkv, ushort_t* __restrict__ ctx)
{
  __shared__ float    S[64 * SST];
  __shared__ ushort_t Vt[128 * VST];
  const int tid = threadIdx.x, lane = tid & 63, wave = tid >> 6;
  const int fr = lane & 15, q = lane >> 4;
  const int hh = blockIdx.x, bb = blockIdx.y;
  const size_t base = (size_t)bb * T_ * DQ_;
  const ushort_t* Qb = qkv + base + hh * HD_;
  const ushort_t* Kb = qkv + base + D_ + hh * HD_;
  const ushort_t* Vb = qkv + base + 2 * D_ + hh * HD_;

  for (int e = tid; e < T_ * HD_; e += 256) {
    const int j = e >> 7, d = e & 127;
    Vt[d * VST + j] = Vb[(size_t)j * DQ_ + d];
  }
  for (int e = tid; e < 128 * 20; e += 256) {
    const int d = e / 20, j = e - d * 20;
    Vt[d * VST + 100 + j] = 0;
  }

  for (int c = 0; c < 2; c++) {
    __syncthreads();
    const int it  = c * 4 + wave;
    const bool wlive = (it < 7);
    const int itc = wlive ? it : 6;
    const int qrow = min(itc * 16 + fr, T_ - 1);
    f32x4 sacc[7];
    #pragma unroll
    for (int jt = 0; jt < 7; jt++) sacc[jt] = 0.f;
    #pragma unroll
    for (int ks = 0; ks < 4; ks++) {
      const int kk = ks * 32 + q * 8;
      const bf16x8 aq = *(const bf16x8*)(Qb + (size_t)qrow * DQ_ + kk);
      #pragma unroll
      for (int jt = 0; jt < 7; jt++) {
        const int kr = min(jt * 16 + fr, T_ - 1);
        const bf16x8 kb = *(const bf16x8*)(Kb + (size_t)kr * DQ_ + kk);
        sacc[jt] = __builtin_amdgcn_mfma_f32_16x16x32_bf16(aq, kb, sacc[jt], 0, 0, 0);
      }
    }
    if (wlive) {
      #pragma unroll
      for (int jt = 0; jt < 7; jt++) {
        const int colb = jt * 16 + fr;
        #pragma unroll
        for (int rr = 0; rr < 4; rr++)
          S[(wave * 16 + q * 4 + rr) * SST + colb] = sacc[jt][rr] * SCALE_;
      }
    }
    __syncthreads();
    if (tid < 64) {
      float4* row = (float4*)&S[tid * SST];
      float m = -1e30f;
      for (int jj = 0; jj < 25; jj++) {
        const float4 v = row[jj];
        m = fmaxf(m, fmaxf(fmaxf(v.x, v.y), fmaxf(v.z, v.w)));
      }
      float s = 0.f;
      for (int jj = 0; jj < 25; jj++) {
        float4 v = row[jj];
        v.x = __expf(v.x - m); v.y = __expf(v.y - m);
        v.z = __expf(v.z - m); v.w = __expf(v.w - m);
        s += v.x + v.y + v.z + v.w;
        row[jj] = v;
      }
      const float inv = 1.f / s;
      for (int jj = 0; jj < 25; jj++) {
        float4 v = row[jj];
        v.x *= inv; v.y *= inv; v.z *= inv; v.w *= inv;
        row[jj] = v;
      }
      row[25] = (float4){0.f,0.f,0.f,0.f};
      row[26] = (float4){0.f,0.f,0.f,0.f};
      row[27] = (float4){0.f,0.f,0.f,0.f};
    }
    __syncthreads();
    const int mtc = (c == 0) ? 4 : 3;
    f32x4 cacc[4][2];
    #pragma unroll
    for (int i = 0; i < 4; i++) { cacc[i][0] = 0.f; cacc[i][1] = 0.f; }
    #pragma unroll
    for (int ks = 0; ks < 4; ks++) {
      const int kk = ks * 32 + q * 8;
      const bool live = (ks < 3) || (q < 2);
      bf16x8 v0 = 0, v1 = 0;
      if (live) {
        v0 = *(const bf16x8*)&Vt[((wave * 2 + 0) * 16 + fr) * VST + kk];
        v1 = *(const bf16x8*)&Vt[((wave * 2 + 1) * 16 + fr) * VST + kk];
      }
      for (int mt = 0; mt < mtc; mt++) {
        bf16x8 a = 0;
        if (live) {
          const float* pr = &S[(mt * 16 + fr) * SST + kk];
          const float4 p0 = *(const float4*)pr;
          const float4 p1 = *(const float4*)(pr + 4);
          a[0] = (short)f2bf(p0.x); a[1] = (short)f2bf(p0.y);
          a[2] = (short)f2bf(p0.z); a[3] = (short)f2bf(p0.w);
          a[4] = (short)f2bf(p1.x); a[5] = (short)f2bf(p1.y);
          a[6] = (short)f2bf(p1.z); a[7] = (short)f2bf(p1.w);
        }
        cacc[mt][0] = __builtin_amdgcn_mfma_f32_16x16x32_bf16(a, v0, cacc[mt][0], 0, 0, 0);
        cacc[mt][1] = __builtin_amdgcn_mfma_f32_16x16x32_bf16(a, v1, cacc[mt][1], 0, 0, 0);
      }
    }
    for (int mt = 0; mt < mtc; mt++) {
      #pragma unroll
      for (int nn = 0; nn < 2; nn++) {
        const int col = hh * HD_ + (wave * 2 + nn) * 16 + fr;
        #pragma unroll
        for (int rr = 0; rr < 4; rr++) {
          const int r = c * 64 + mt * 16 + q * 4 + rr;
          if (r < T_)
            ctx[(size_t)(bb * T_ + r) * D_ + col] = f2bf(cacc[mt][nn][rr]);
        }
      }
    }
  }
}

// ---------------------------------------------------------------------------
// LayerNorm: bf16 in -> bf16 out (fp32 stats). One block per row.
// ---------------------------------------------------------------------------
__global__ __launch_bounds__(256)
void ln_kernel(const ushort_t* __restrict__ in, ushort_t* __restrict__ outb,
               const float* __restrict__ g, const float* __restrict__ bta)
{
  const int row = blockIdx.x, tid = threadIdx.x;
  const int c4 = tid * 4;
  const ushort4 uv = *(const ushort4*)(in + (size_t)row * D_ + c4);
  const float v0 = bf2f(uv.x), v1 = bf2f(uv.y), v2 = bf2f(uv.z), v3 = bf2f(uv.w);
  float s  = v0 + v1 + v2 + v3;
  float ss = v0*v0 + v1*v1 + v2*v2 + v3*v3;
  #pragma unroll
  for (int o = 1; o < 64; o <<= 1) {
    s  += __shfl_xor(s, o);
    ss += __shfl_xor(ss, o);
  }
  __shared__ float red[8];
  const int lane = tid & 63, wave = tid >> 6;
  if (lane == 0) { red[wave] = s; red[4 + wave] = ss; }
  __syncthreads();
  s  = red[0] + red[1] + red[2] + red[3];
  ss = red[4] + red[5] + red[6] + red[7];
  const float mean = s * (1.f / D_);
  const float var  = ss * (1.f / D_) - mean * mean;
  const float rstd = rsqrtf(var + 1e-5f);
  const float4 gv = *(const float4*)(g + c4);
  const float4 bv = *(const float4*)(bta + c4);
  ushort4 ob = { f2bf((v0 - mean) * rstd * gv.x + bv.x),
                 f2bf((v1 - mean) * rstd * gv.y + bv.y),
                 f2bf((v2 - mean) * rstd * gv.z + bv.z),
                 f2bf((v3 - mean) * rstd * gv.w + bv.w) };
  *(ushort4*)(outb + (size_t)row * D_ + c4) = ob;
}

// ---------------------------------------------------------------------------
// Embedding: h = x@Wi + bi + PE(t,:) -> bf16. One block per token row.
// ---------------------------------------------------------------------------
__global__ __launch_bounds__(256)
void embed_kernel(const float* __restrict__ x, const float* __restrict__ Wi,
                  const float* __restrict__ bi, ushort_t* hbf)
{
  const int row = blockIdx.x;
  const int t = row % T_;
  const int c = threadIdx.x * 4;
  float xv[6];
  #pragma unroll
  for (int i = 0; i < 6; i++) xv[i] = x[row * 6 + i];
  ushort4 ob;
  ushort_t* obp = (ushort_t*)&ob;
  #pragma unroll
  for (int u = 0; u < 4; u++) {
    const int d = c + u;
    float a = bi[d];
    #pragma unroll
    for (int i = 0; i < 6; i++) a += xv[i] * Wi[i * D_ + d];
    const int k = d >> 1;
    const float ang = (float)t * expf((float)k * -0.017988946039015984f); // -ln(1e4)/512
    a += (d & 1) ? cosf(ang) : sinf(ang);
    obp[u] = f2bf(a);
  }
  *(ushort4*)(hbf + (size_t)row * D_ + c) = ob;
}

// All weight tensors -> bf16 in one launch.
#define NQW (L_*DQ_*D_)   // 12582912
#define NDW (L_*D_*D_)    //  4194304
__global__ void cvt_all(const float* __restrict__ qw, const float* __restrict__ ow,
                        const float* __restrict__ f1, const float* __restrict__ f2,
                        ushort_t* wq, ushort_t* wo, ushort_t* w1, ushort_t* w2)
{
  const size_t i = ((size_t)blockIdx.x * 256 + threadIdx.x) * 4;
  const float* s; ushort_t* d; size_t off;
  if (i < NQW)                { s = qw; d = wq; off = i; }
  else if (i < NQW + NDW)     { s = ow; d = wo; off = i - NQW; }
  else if (i < NQW + 2*NDW)   { s = f1; d = w1; off = i - NQW - NDW; }
  else                        { s = f2; d = w2; off = i - NQW - 2*NDW; }
  const float4 v = *(const float4*)(s + off);
  ushort4 o = { f2bf(v.x), f2bf(v.y), f2bf(v.z), f2bf(v.w) };
  *(ushort4*)(d + off) = o;
}

// Wo [KFIN,256] fp32 -> Wot [256,KFIN] bf16
__global__ __launch_bounds__(256)
void transpose_wo(const float* __restrict__ src, ushort_t* __restrict__ dst)
{
  __shared__ float tile[64][65];
  const int k0 = blockIdx.x * 64, n0 = blockIdx.y * 64;
  const int tc = threadIdx.x & 63, tr = threadIdx.x >> 6;
  #pragma unroll
  for (int i = 0; i < 16; i++) {
    const int r = i * 4 + tr;
    tile[r][tc] = src[(size_t)(k0 + r) * OUT_ + n0 + tc];
  }
  __syncthreads();
  #pragma unroll
  for (int i = 0; i < 16; i++) {
    const int n = i * 4 + tr;
    dst[(size_t)(n0 + n) * KFIN_ + k0 + tc] = f2bf(tile[tc][n]);
  }
}

__global__ void reduce_final(const float* __restrict__ part,
                             const float* __restrict__ bo, float* __restrict__ out)
{
  const int i = blockIdx.x * 256 + threadIdx.x;   // 65536 outputs
  float s = bo[i & (OUT_ - 1)];
  for (int z = 0; z < KSPLIT_; z++) s += part[(size_t)z * OUT_ * OUT_ + i];
  out[i] = s;
}

// ---------------------------------------------------------------------------
extern "C" void kernel_launch(void* const* d_in, const int* in_sizes, int n_in,
                              void* d_out, int out_size, void* d_ws, size_t ws_size,
                              hipStream_t stream)
{
  (void)in_sizes; (void)n_in; (void)out_size; (void)ws_size;
  const float* x     = (const float*)d_in[0];
  const float* Wi    = (const float*)d_in[1];
  const float* bi    = (const float*)d_in[2];
  const float* qkv_w = (const float*)d_in[3];
  const float* qkv_b = (const float*)d_in[4];
  const float* out_w = (const float*)d_in[5];
  const float* out_b = (const float*)d_in[6];
  const float* ff1_w = (const float*)d_in[7];
  const float* ff1_b = (const float*)d_in[8];
  const float* ff2_w = (const float*)d_in[9];
  const float* ff2_b = (const float*)d_in[10];
  const float* ln1_g = (const float*)d_in[11];
  const float* ln1_b = (const float*)d_in[12];
  const float* ln2_g = (const float*)d_in[13];
  const float* ln2_b = (const float*)d_in[14];
  const float* Wo    = (const float*)d_in[15];
  const float* bo    = (const float*)d_in[16];
  float* out = (float*)d_out;

  // workspace layout — 312 MiB peak
  char* p = (char*)d_ws;
  ushort_t* hbf  = (ushort_t*)p; p += (size_t)BT_ * D_ * 2;     //  52.4 MB
  ushort_t* qkvb = (ushort_t*)p; p += (size_t)BT_ * DQ_ * 2;    // 157.3 MB
  ushort_t* ctxb = (ushort_t*)p; p += (size_t)BT_ * D_ * 2;     //  52.4 MB
  ushort_t* wq   = (ushort_t*)p; p += (size_t)NQW * 2;          //  25.2 MB
  ushort_t* wo   = (ushort_t*)p; p += (size_t)NDW * 2;          //   8.4 MB
  ushort_t* w1   = (ushort_t*)p; p += (size_t)NDW * 2;          //   8.4 MB
  ushort_t* w2   = (ushort_t*)p; p += (size_t)NDW * 2;          //   8.4 MB
  ushort_t* ffact = qkvb;                         // qkv dead after attention
  ushort_t* sum   = qkvb + (size_t)BT_ * D_;      // pre-LN sum (slot 1)
  ushort_t* wot   = ctxb;                         // ctx dead after last out-proj
  float*    part  = (float*)qkvb;                 // final split-K partials

  cvt_all<<<dim3((NQW + 3*NDW) / 1024), 256, 0, stream>>>(
      qkv_w, out_w, ff1_w, ff2_w, wq, wo, w1, w2);
  embed_kernel<<<dim3(BT_), 256, 0, stream>>>(x, Wi, bi, hbf);

  for (int i = 0; i < L_; i++) {
    // qkv = h @ qkv_w^T + b  -> bf16
    gemm_nt<0,0,1,0><<<dim3(DQ_/128, BT_/128, 1), 256, 0, stream>>>(
        hbf, wq + (size_t)i * DQ_ * D_, qkv_b + i * DQ_,
        qkvb, nullptr, nullptr, BT_, DQ_, D_, D_ / 32);
    attn_kernel<<<dim3(H_, B_), 256, 0, stream>>>(qkvb, ctxb);
    // sum = ctx @ out_w^T + b + h   (bf16)
    gemm_nt<0,1,1,0><<<dim3(D_/128, BT_/128, 1), 256, 0, stream>>>(
        ctxb, wo + (size_t)i * D_ * D_, out_b + i * D_,
        sum, nullptr, hbf, BT_, D_, D_, D_ / 32);
    ln_kernel<<<dim3(BT_), 256, 0, stream>>>(sum, hbf, ln1_g + i * D_, ln1_b + i * D_);
    // ff = relu(h @ ff1^T + b) -> bf16
    gemm_nt<1,0,1,0><<<dim3(D_/128, BT_/128, 1), 256, 0, stream>>>(
        hbf, w1 + (size_t)i * D_ * D_, ff1_b + i * D_,
        ffact, nullptr, nullptr, BT_, D_, D_, D_ / 32);
    // sum = ff @ ff2^T + b + h   (bf16)
    gemm_nt<0,1,1,0><<<dim3(D_/128, BT_/128, 1), 256, 0, stream>>>(
        ffact, w2 + (size_t)i * D_ * D_, ff2_b + i * D_,
        sum, nullptr, hbf, BT_, D_, D_, D_ / 32);
    ln_kernel<<<dim3(BT_), 256, 0, stream>>>(sum, hbf, ln2_g + i * D_, ln2_b + i * D_);
  }

  // final: out = h.reshape(256,102400) @ Wo + bo   (split-K partials + reduce)
  transpose_wo<<<dim3(KFIN_/64, OUT_/64), 256, 0, stream>>>(Wo, wot);
  gemm_nt<0,0,0,1><<<dim3(OUT_/128, OUT_/128, KSPLIT_), 256, 0, stream>>>(
      hbf, wot, nullptr, nullptr, part, nullptr,
      OUT_, OUT_, KFIN_, KFIN_ / (KSPLIT_ * 32));
  reduce_final<<<dim3(OUT_ * OUT_ / 256), 256, 0, stream>>>(part, bo, out);
}

// Round 4
// 3324.899 us; speedup vs baseline: 1.2391x; 1.0277x over previous
//
#include <hip/hip_runtime.h>

// TrajectoryTransformer fused bf16-MFMA implementation for MI355X (gfx950).
// B=256 T=100 IN=6 D=1024 H=8 HD=128 L=4 OUT=256.
// Mask in reference is constant along softmax axis -> provable no-op -> dropped.
// R4: BK=64 K-loop (halve barrier-drain count; 32KB LDS keeps occupancy).
//     Single-variable experiment vs R3.

#define B_    256
#define T_    100
#define D_    1024
#define H_    8
#define HD_   128
#define L_    4
#define BT_   25600          // B*T
#define DQ_   3072           // 3*D
#define OUT_  256
#define KFIN_ 102400         // T*D
#define KSPLIT_ 32
#define SCALE_ 0.08838834764831845f  // 1/sqrt(128)

typedef unsigned short ushort_t;
typedef __attribute__((ext_vector_type(8))) short bf16x8;   // 8 bf16 (4 VGPRs)
typedef __attribute__((ext_vector_type(4))) float f32x4;    // MFMA C/D

__device__ inline ushort_t f2bf(float f) {   // RNE fp32 -> bf16
  unsigned u = __float_as_uint(f);
  u += 0x7FFFu + ((u >> 16) & 1u);
  return (ushort_t)(u >> 16);
}
__device__ inline float bf2f(ushort_t u) {
  return __uint_as_float((unsigned)u << 16);
}

// async global->LDS, 16B per lane; LDS dest is wave-uniform base + lane*16
__device__ inline void gld16(const void* g, void* l) {
  __builtin_amdgcn_global_load_lds(
      (__attribute__((address_space(1))) unsigned int*)(size_t)g,
      (__attribute__((address_space(3))) unsigned int*)l, 16, 0, 0);
}

// ---------------------------------------------------------------------------
// C[m,n] = sum_k A[m,k]*Bw[n,k] (+bias, relu, bf16-resid; bf16 or f32-partial out)
// A:[M,K] bf16 row-major, Bw:[N,K] bf16 row-major. 128x128 tile, BK=64.
// Tile LDS layout: chunk c (16B) holds row r=c>>3, k-slot c&7 where the k-group
// kg = (c&7) ^ (r&7)  (xor swizzle; for stage-inst i, chunks c=i*64+lane give
// r = i*8+(lane>>3) so kg depends only on lane: (lane&7)^(lane>>3)).
// grid: (N/128, M/128, ksplit). OF32 writes fp32 partial at z*M*N offset.
// ---------------------------------------------------------------------------
template<int RELU, int RESID, int OBF, int OF32>
__global__ __launch_bounds__(256)
void gemm_nt(const ushort_t* __restrict__ A, const ushort_t* __restrict__ Bw,
             const float* __restrict__ bias,
             ushort_t* outb, float* outf, const ushort_t* __restrict__ resid,
             int M, int N, int K, int ksteps)
{
  __shared__ ushort_t lds[16384];      // A: [0,8192), B: [8192,16384)  (32 KB)
  ushort_t* lsA = lds;
  ushort_t* lsB = lds + 8192;
  const int tid = threadIdx.x, lane = tid & 63, wave = tid >> 6;
  const int fr = lane & 15, q = lane >> 4;
  const int m0 = blockIdx.y * 128, n0 = blockIdx.x * 128;
  const int wm = (wave >> 1) * 64, wn = (wave & 1) * 64;
  const int kbase = blockIdx.z * ksteps * 64;

  const ushort_t* Ab = A + (size_t)m0 * K + kbase;
  const ushort_t* Bb = Bw + (size_t)n0 * K + kbase;

  // per-lane staging source base (inst i adds i*8 rows)
  const int kg = (lane & 7) ^ (lane >> 3);
  const ushort_t* gaA = Ab + (size_t)(lane >> 3) * K + kg * 8;
  const ushort_t* gaB = Bb + (size_t)(lane >> 3) * K + kg * 8;

  f32x4 acc[4][4];
  #pragma unroll
  for (int i = 0; i < 4; i++)
    #pragma unroll
    for (int j = 0; j < 4; j++) acc[i][j] = 0.f;

  // fragment-read LDS offsets (ushort units): row*64 + slot*8,
  // slot = (s*4+q) ^ (fr&7) — t-independent (wm/wn/t*16 are 0 mod 8)
  int rowA[4], rowB[4];
  #pragma unroll
  for (int t = 0; t < 4; t++) {
    rowA[t] = (wm + t * 16 + fr) * 64;
    rowB[t] = (wn + t * 16 + fr) * 64;
  }
  const int sl0 = ((0 * 4 + q) ^ (fr & 7)) * 8;
  const int sl1 = ((1 * 4 + q) ^ (fr & 7)) * 8;

  for (int ks = 0; ks < ksteps; ks++) {
    __syncthreads();
    #pragma unroll
    for (int u = 0; u < 4; u++) {
      const int i = wave * 4 + u;
      gld16(gaA + ks * 64 + (size_t)i * 8 * K, lsA + i * 512);
      gld16(gaB + ks * 64 + (size_t)i * 8 * K, lsB + i * 512);
    }
    __syncthreads();
    #pragma unroll
    for (int s = 0; s < 2; s++) {
      const int sl = s ? sl1 : sl0;
      bf16x8 af[4], bfv[4];
      #pragma unroll
      for (int t = 0; t < 4; t++) {
        af[t]  = *(const bf16x8*)(lsA + rowA[t] + sl);
        bfv[t] = *(const bf16x8*)(lsB + rowB[t] + sl);
      }
      #pragma unroll
      for (int i = 0; i < 4; i++)
        #pragma unroll
        for (int j = 0; j < 4; j++)
          acc[i][j] = __builtin_amdgcn_mfma_f32_16x16x32_bf16(af[i], bfv[j], acc[i][j], 0, 0, 0);
    }
  }

  // C/D layout col=lane&15, row=(lane>>4)*4+reg (m89/m91-verified)
  if (OBF) {
    __syncthreads();                     // staging LDS now dead for all waves
    ushort_t* myl = lds + wave * 2048;   // private 4KB per wave
    const int rloc = lane >> 2, cg = lane & 3;
    #pragma unroll
    for (int hh = 0; hh < 2; hh++) {     // column halves (32 cols each)
      #pragma unroll
      for (int j2 = 0; j2 < 2; j2++) {
        const int j = 2 * hh + j2;
        const float bv = bias ? bias[n0 + wn + j * 16 + fr] : 0.f;
        #pragma unroll
        for (int i = 0; i < 4; i++) {
          #pragma unroll
          for (int rr = 0; rr < 4; rr++) {
            const int row = i * 16 + q * 4 + rr;
            const int col = j2 * 16 + fr;       // 0..31
            float v = acc[i][j][rr] + bv;
            if (RELU) v = fmaxf(v, 0.f);
            const int cgw = col >> 3, cwi = col & 7;
            myl[(row * 4 + (cgw ^ (row & 3) ^ ((row >> 2) & 3))) * 8 + cwi] = f2bf(v);
          }
        }
      }
      // read back 16B row-segments, wide coalesced stores (+bf16 resid)
      #pragma unroll
      for (int rb = 0; rb < 4; rb++) {
        const int row = rb * 16 + rloc;
        const int cgr = cg ^ (row & 3) ^ ((row >> 2) & 3);
        bf16x8 seg = *(const bf16x8*)&myl[(row * 4 + cgr) * 8];
        const size_t gaddr = (size_t)(m0 + wm + row) * N + (n0 + wn + hh * 32 + cg * 8);
        if (RESID) {
          const bf16x8 rv = *(const bf16x8*)&resid[gaddr];
          #pragma unroll
          for (int e = 0; e < 8; e++) {
            const float f = bf2f((ushort_t)seg[e]) + bf2f((ushort_t)rv[e]);
            seg[e] = (short)f2bf(f);
          }
        }
        *(bf16x8*)&outb[gaddr] = seg;
      }
    }
  }
  if (OF32) {  // fp32 split-K partial (final GEMM only; small output)
    float* po = outf + (size_t)blockIdx.z * M * N;
    #pragma unroll
    for (int i = 0; i < 4; i++) {
      const int rb = m0 + wm + i * 16 + q * 4;
      #pragma unroll
      for (int j = 0; j < 4; j++) {
        const int col = n0 + wn + j * 16 + fr;
        #pragma unroll
        for (int rr = 0; rr < 4; rr++)
          po[(size_t)(rb + rr) * N + col] = acc[i][j][rr];
      }
    }
  }
}

// ---------------------------------------------------------------------------
// Fused attention: one block per (head, batch). qkv:[BT,3072] bf16.
// ---------------------------------------------------------------------------
#define SST 116   // S row stride (floats)
#define VST 120   // Vt row stride (bf16)

__global__ __launch_bounds__(256)
void attn_kernel(const ushort_t* __restrict__ qkv, ushort_t* __restrict__ ctx)
{
  __shared__ float    S[64 * SST];
  __shared__ ushort_t Vt[128 * VST];
  const int tid = threadIdx.x, lane = tid & 63, wave = tid >> 6;
  const int fr = lane & 15, q = lane >> 4;
  const int hh = blockIdx.x, bb = blockIdx.y;
  const size_t base = (size_t)bb * T_ * DQ_;
  const ushort_t* Qb = qkv + base + hh * HD_;
  const ushort_t* Kb = qkv + base + D_ + hh * HD_;
  const ushort_t* Vb = qkv + base + 2 * D_ + hh * HD_;

  for (int e = tid; e < T_ * HD_; e += 256) {
    const int j = e >> 7, d = e & 127;
    Vt[d * VST + j] = Vb[(size_t)j * DQ_ + d];
  }
  for (int e = tid; e < 128 * 20; e += 256) {
    const int d = e / 20, j = e - d * 20;
    Vt[d * VST + 100 + j] = 0;
  }

  for (int c = 0; c < 2; c++) {
    __syncthreads();
    const int it  = c * 4 + wave;
    const bool wlive = (it < 7);
    const int itc = wlive ? it : 6;
    const int qrow = min(itc * 16 + fr, T_ - 1);
    f32x4 sacc[7];
    #pragma unroll
    for (int jt = 0; jt < 7; jt++) sacc[jt] = 0.f;
    #pragma unroll
    for (int ks = 0; ks < 4; ks++) {
      const int kk = ks * 32 + q * 8;
      const bf16x8 aq = *(const bf16x8*)(Qb + (size_t)qrow * DQ_ + kk);
      #pragma unroll
      for (int jt = 0; jt < 7; jt++) {
        const int kr = min(jt * 16 + fr, T_ - 1);
        const bf16x8 kb = *(const bf16x8*)(Kb + (size_t)kr * DQ_ + kk);
        sacc[jt] = __builtin_amdgcn_mfma_f32_16x16x32_bf16(aq, kb, sacc[jt], 0, 0, 0);
      }
    }
    if (wlive) {
      #pragma unroll
      for (int jt = 0; jt < 7; jt++) {
        const int colb = jt * 16 + fr;
        #pragma unroll
        for (int rr = 0; rr < 4; rr++)
          S[(wave * 16 + q * 4 + rr) * SST + colb] = sacc[jt][rr] * SCALE_;
      }
    }
    __syncthreads();
    if (tid < 64) {
      float4* row = (float4*)&S[tid * SST];
      float m = -1e30f;
      for (int jj = 0; jj < 25; jj++) {
        const float4 v = row[jj];
        m = fmaxf(m, fmaxf(fmaxf(v.x, v.y), fmaxf(v.z, v.w)));
      }
      float s = 0.f;
      for (int jj = 0; jj < 25; jj++) {
        float4 v = row[jj];
        v.x = __expf(v.x - m); v.y = __expf(v.y - m);
        v.z = __expf(v.z - m); v.w = __expf(v.w - m);
        s += v.x + v.y + v.z + v.w;
        row[jj] = v;
      }
      const float inv = 1.f / s;
      for (int jj = 0; jj < 25; jj++) {
        float4 v = row[jj];
        v.x *= inv; v.y *= inv; v.z *= inv; v.w *= inv;
        row[jj] = v;
      }
      row[25] = (float4){0.f,0.f,0.f,0.f};
      row[26] = (float4){0.f,0.f,0.f,0.f};
      row[27] = (float4){0.f,0.f,0.f,0.f};
    }
    __syncthreads();
    const int mtc = (c == 0) ? 4 : 3;
    f32x4 cacc[4][2];
    #pragma unroll
    for (int i = 0; i < 4; i++) { cacc[i][0] = 0.f; cacc[i][1] = 0.f; }
    #pragma unroll
    for (int ks = 0; ks < 4; ks++) {
      const int kk = ks * 32 + q * 8;
      const bool live = (ks < 3) || (q < 2);
      bf16x8 v0 = 0, v1 = 0;
      if (live) {
        v0 = *(const bf16x8*)&Vt[((wave * 2 + 0) * 16 + fr) * VST + kk];
        v1 = *(const bf16x8*)&Vt[((wave * 2 + 1) * 16 + fr) * VST + kk];
      }
      for (int mt = 0; mt < mtc; mt++) {
        bf16x8 a = 0;
        if (live) {
          const float* pr = &S[(mt * 16 + fr) * SST + kk];
          const float4 p0 = *(const float4*)pr;
          const float4 p1 = *(const float4*)(pr + 4);
          a[0] = (short)f2bf(p0.x); a[1] = (short)f2bf(p0.y);
          a[2] = (short)f2bf(p0.z); a[3] = (short)f2bf(p0.w);
          a[4] = (short)f2bf(p1.x); a[5] = (short)f2bf(p1.y);
          a[6] = (short)f2bf(p1.z); a[7] = (short)f2bf(p1.w);
        }
        cacc[mt][0] = __builtin_amdgcn_mfma_f32_16x16x32_bf16(a, v0, cacc[mt][0], 0, 0, 0);
        cacc[mt][1] = __builtin_amdgcn_mfma_f32_16x16x32_bf16(a, v1, cacc[mt][1], 0, 0, 0);
      }
    }
    for (int mt = 0; mt < mtc; mt++) {
      #pragma unroll
      for (int nn = 0; nn < 2; nn++) {
        const int col = hh * HD_ + (wave * 2 + nn) * 16 + fr;
        #pragma unroll
        for (int rr = 0; rr < 4; rr++) {
          const int r = c * 64 + mt * 16 + q * 4 + rr;
          if (r < T_)
            ctx[(size_t)(bb * T_ + r) * D_ + col] = f2bf(cacc[mt][nn][rr]);
        }
      }
    }
  }
}

// ---------------------------------------------------------------------------
// LayerNorm: bf16 in -> bf16 out (fp32 stats). One block per row.
// ---------------------------------------------------------------------------
__global__ __launch_bounds__(256)
void ln_kernel(const ushort_t* __restrict__ in, ushort_t* __restrict__ outb,
               const float* __restrict__ g, const float* __restrict__ bta)
{
  const int row = blockIdx.x, tid = threadIdx.x;
  const int c4 = tid * 4;
  const ushort4 uv = *(const ushort4*)(in + (size_t)row * D_ + c4);
  const float v0 = bf2f(uv.x), v1 = bf2f(uv.y), v2 = bf2f(uv.z), v3 = bf2f(uv.w);
  float s  = v0 + v1 + v2 + v3;
  float ss = v0*v0 + v1*v1 + v2*v2 + v3*v3;
  #pragma unroll
  for (int o = 1; o < 64; o <<= 1) {
    s  += __shfl_xor(s, o);
    ss += __shfl_xor(ss, o);
  }
  __shared__ float red[8];
  const int lane = tid & 63, wave = tid >> 6;
  if (lane == 0) { red[wave] = s; red[4 + wave] = ss; }
  __syncthreads();
  s  = red[0] + red[1] + red[2] + red[3];
  ss = red[4] + red[5] + red[6] + red[7];
  const float mean = s * (1.f / D_);
  const float var  = ss * (1.f / D_) - mean * mean;
  const float rstd = rsqrtf(var + 1e-5f);
  const float4 gv = *(const float4*)(g + c4);
  const float4 bv = *(const float4*)(bta + c4);
  ushort4 ob = { f2bf((v0 - mean) * rstd * gv.x + bv.x),
                 f2bf((v1 - mean) * rstd * gv.y + bv.y),
                 f2bf((v2 - mean) * rstd * gv.z + bv.z),
                 f2bf((v3 - mean) * rstd * gv.w + bv.w) };
  *(ushort4*)(outb + (size_t)row * D_ + c4) = ob;
}

// ---------------------------------------------------------------------------
// Embedding: h = x@Wi + bi + PE(t,:) -> bf16. One block per token row.
// ---------------------------------------------------------------------------
__global__ __launch_bounds__(256)
void embed_kernel(const float* __restrict__ x, const float* __restrict__ Wi,
                  const float* __restrict__ bi, ushort_t* hbf)
{
  const int row = blockIdx.x;
  const int t = row % T_;
  const int c = threadIdx.x * 4;
  float xv[6];
  #pragma unroll
  for (int i = 0; i < 6; i++) xv[i] = x[row * 6 + i];
  ushort4 ob;
  ushort_t* obp = (ushort_t*)&ob;
  #pragma unroll
  for (int u = 0; u < 4; u++) {
    const int d = c + u;
    float a = bi[d];
    #pragma unroll
    for (int i = 0; i < 6; i++) a += xv[i] * Wi[i * D_ + d];
    const int k = d >> 1;
    const float ang = (float)t * expf((float)k * -0.017988946039015984f); // -ln(1e4)/512
    a += (d & 1) ? cosf(ang) : sinf(ang);
    obp[u] = f2bf(a);
  }
  *(ushort4*)(hbf + (size_t)row * D_ + c) = ob;
}

// All weight tensors -> bf16 in one launch.
#define NQW (L_*DQ_*D_)   // 12582912
#define NDW (L_*D_*D_)    //  4194304
__global__ void cvt_all(const float* __restrict__ qw, const float* __restrict__ ow,
                        const float* __restrict__ f1, const float* __restrict__ f2,
                        ushort_t* wq, ushort_t* wo, ushort_t* w1, ushort_t* w2)
{
  const size_t i = ((size_t)blockIdx.x * 256 + threadIdx.x) * 4;
  const float* s; ushort_t* d; size_t off;
  if (i < NQW)                { s = qw; d = wq; off = i; }
  else if (i < NQW + NDW)     { s = ow; d = wo; off = i - NQW; }
  else if (i < NQW + 2*NDW)   { s = f1; d = w1; off = i - NQW - NDW; }
  else                        { s = f2; d = w2; off = i - NQW - 2*NDW; }
  const float4 v = *(const float4*)(s + off);
  ushort4 o = { f2bf(v.x), f2bf(v.y), f2bf(v.z), f2bf(v.w) };
  *(ushort4*)(d + off) = o;
}

// Wo [KFIN,256] fp32 -> Wot [256,KFIN] bf16
__global__ __launch_bounds__(256)
void transpose_wo(const float* __restrict__ src, ushort_t* __restrict__ dst)
{
  __shared__ float tile[64][65];
  const int k0 = blockIdx.x * 64, n0 = blockIdx.y * 64;
  const int tc = threadIdx.x & 63, tr = threadIdx.x >> 6;
  #pragma unroll
  for (int i = 0; i < 16; i++) {
    const int r = i * 4 + tr;
    tile[r][tc] = src[(size_t)(k0 + r) * OUT_ + n0 + tc];
  }
  __syncthreads();
  #pragma unroll
  for (int i = 0; i < 16; i++) {
    const int n = i * 4 + tr;
    dst[(size_t)(n0 + n) * KFIN_ + k0 + tc] = f2bf(tile[tc][n]);
  }
}

__global__ void reduce_final(const float* __restrict__ part,
                             const float* __restrict__ bo, float* __restrict__ out)
{
  const int i = blockIdx.x * 256 + threadIdx.x;   // 65536 outputs
  float s = bo[i & (OUT_ - 1)];
  for (int z = 0; z < KSPLIT_; z++) s += part[(size_t)z * OUT_ * OUT_ + i];
  out[i] = s;
}

// ---------------------------------------------------------------------------
extern "C" void kernel_launch(void* const* d_in, const int* in_sizes, int n_in,
                              void* d_out, int out_size, void* d_ws, size_t ws_size,
                              hipStream_t stream)
{
  (void)in_sizes; (void)n_in; (void)out_size; (void)ws_size;
  const float* x     = (const float*)d_in[0];
  const float* Wi    = (const float*)d_in[1];
  const float* bi    = (const float*)d_in[2];
  const float* qkv_w = (const float*)d_in[3];
  const float* qkv_b = (const float*)d_in[4];
  const float* out_w = (const float*)d_in[5];
  const float* out_b = (const float*)d_in[6];
  const float* ff1_w = (const float*)d_in[7];
  const float* ff1_b = (const float*)d_in[8];
  const float* ff2_w = (const float*)d_in[9];
  const float* ff2_b = (const float*)d_in[10];
  const float* ln1_g = (const float*)d_in[11];
  const float* ln1_b = (const float*)d_in[12];
  const float* ln2_g = (const float*)d_in[13];
  const float* ln2_b = (const float*)d_in[14];
  const float* Wo    = (const float*)d_in[15];
  const float* bo    = (const float*)d_in[16];
  float* out = (float*)d_out;

  // workspace layout — 312 MiB peak
  char* p = (char*)d_ws;
  ushort_t* hbf  = (ushort_t*)p; p += (size_t)BT_ * D_ * 2;     //  52.4 MB
  ushort_t* qkvb = (ushort_t*)p; p += (size_t)BT_ * DQ_ * 2;    // 157.3 MB
  ushort_t* ctxb = (ushort_t*)p; p += (size_t)BT_ * D_ * 2;     //  52.4 MB
  ushort_t* wq   = (ushort_t*)p; p += (size_t)NQW * 2;          //  25.2 MB
  ushort_t* wo   = (ushort_t*)p; p += (size_t)NDW * 2;          //   8.4 MB
  ushort_t* w1   = (ushort_t*)p; p += (size_t)NDW * 2;          //   8.4 MB
  ushort_t* w2   = (ushort_t*)p; p += (size_t)NDW * 2;          //   8.4 MB
  ushort_t* ffact = qkvb;                         // qkv dead after attention
  ushort_t* sum   = qkvb + (size_t)BT_ * D_;      // pre-LN sum (slot 1)
  ushort_t* wot   = ctxb;                         // ctx dead after last out-proj
  float*    part  = (float*)qkvb;                 // final split-K partials

  cvt_all<<<dim3((NQW + 3*NDW) / 1024), 256, 0, stream>>>(
      qkv_w, out_w, ff1_w, ff2_w, wq, wo, w1, w2);
  embed_kernel<<<dim3(BT_), 256, 0, stream>>>(x, Wi, bi, hbf);

  for (int i = 0; i < L_; i++) {
    // qkv = h @ qkv_w^T + b  -> bf16
    gemm_nt<0,0,1,0><<<dim3(DQ_/128, BT_/128, 1), 256, 0, stream>>>(
        hbf, wq + (size_t)i * DQ_ * D_, qkv_b + i * DQ_,
        qkvb, nullptr, nullptr, BT_, DQ_, D_, D_ / 64);
    attn_kernel<<<dim3(H_, B_), 256, 0, stream>>>(qkvb, ctxb);
    // sum = ctx @ out_w^T + b + h   (bf16)
    gemm_nt<0,1,1,0><<<dim3(D_/128, BT_/128, 1), 256, 0, stream>>>(
        ctxb, wo + (size_t)i * D_ * D_, out_b + i * D_,
        sum, nullptr, hbf, BT_, D_, D_, D_ / 64);
    ln_kernel<<<dim3(BT_), 256, 0, stream>>>(sum, hbf, ln1_g + i * D_, ln1_b + i * D_);
    // ff = relu(h @ ff1^T + b) -> bf16
    gemm_nt<1,0,1,0><<<dim3(D_/128, BT_/128, 1), 256, 0, stream>>>(
        hbf, w1 + (size_t)i * D_ * D_, ff1_b + i * D_,
        ffact, nullptr, nullptr, BT_, D_, D_, D_ / 64);
    // sum = ff @ ff2^T + b + h   (bf16)
    gemm_nt<0,1,1,0><<<dim3(D_/128, BT_/128, 1), 256, 0, stream>>>(
        ffact, w2 + (size_t)i * D_ * D_, ff2_b + i * D_,
        sum, nullptr, hbf, BT_, D_, D_, D_ / 64);
    ln_kernel<<<dim3(BT_), 256, 0, stream>>>(sum, hbf, ln2_g + i * D_, ln2_b + i * D_);
  }

  // final: out = h.reshape(256,102400) @ Wo + bo   (split-K partials + reduce)
  transpose_wo<<<dim3(KFIN_/64, OUT_/64), 256, 0, stream>>>(Wo, wot);
  gemm_nt<0,0,0,1><<<dim3(OUT_/128, OUT_/128, KSPLIT_), 256, 0, stream>>>(
      hbf, wot, nullptr, nullptr, part, nullptr,
      OUT_, OUT_, KFIN_, KFIN_ / (KSPLIT_ * 64));
  reduce_final<<<dim3(OUT_ * OUT_ / 256), 256, 0, stream>>>(part, bo, out);
}

// Round 5
// 2969.915 us; speedup vs baseline: 1.3872x; 1.1195x over previous
//
#include <hip/hip_runtime.h>

// TrajectoryTransformer fused bf16-MFMA implementation for MI355X (gfx950).
// B=256 T=100 IN=6 D=1024 H=8 HD=128 L=4 OUT=256.
// Mask in reference is constant along softmax axis -> provable no-op -> dropped.
// R5: attention redesign — LDS-staged K (coalesced), register softmax
//     (row lives in one wave: shfl_xor quarter reduction), bf16 P buffer
//     (direct ds_read A-fragments, no repack VALU). GEMM path = R4 (BK=64).

#define B_    256
#define T_    100
#define D_    1024
#define H_    8
#define HD_   128
#define L_    4
#define BT_   25600          // B*T
#define DQ_   3072           // 3*D
#define OUT_  256
#define KFIN_ 102400         // T*D
#define KSPLIT_ 32
#define SCALE_ 0.08838834764831845f  // 1/sqrt(128)

typedef unsigned short ushort_t;
typedef __attribute__((ext_vector_type(8))) short bf16x8;   // 8 bf16 (4 VGPRs)
typedef __attribute__((ext_vector_type(4))) float f32x4;    // MFMA C/D

__device__ inline ushort_t f2bf(float f) {   // RNE fp32 -> bf16
  unsigned u = __float_as_uint(f);
  u += 0x7FFFu + ((u >> 16) & 1u);
  return (ushort_t)(u >> 16);
}
__device__ inline float bf2f(ushort_t u) {
  return __uint_as_float((unsigned)u << 16);
}

// async global->LDS, 16B per lane; LDS dest is wave-uniform base + lane*16
__device__ inline void gld16(const void* g, void* l) {
  __builtin_amdgcn_global_load_lds(
      (__attribute__((address_space(1))) unsigned int*)(size_t)g,
      (__attribute__((address_space(3))) unsigned int*)l, 16, 0, 0);
}

// ---------------------------------------------------------------------------
// C[m,n] = sum_k A[m,k]*Bw[n,k] (+bias, relu, bf16-resid; bf16 or f32-partial out)
// A:[M,K] bf16 row-major, Bw:[N,K] bf16 row-major. 128x128 tile, BK=64.
// ---------------------------------------------------------------------------
template<int RELU, int RESID, int OBF, int OF32>
__global__ __launch_bounds__(256)
void gemm_nt(const ushort_t* __restrict__ A, const ushort_t* __restrict__ Bw,
             const float* __restrict__ bias,
             ushort_t* outb, float* outf, const ushort_t* __restrict__ resid,
             int M, int N, int K, int ksteps)
{
  __shared__ ushort_t lds[16384];      // A: [0,8192), B: [8192,16384)  (32 KB)
  ushort_t* lsA = lds;
  ushort_t* lsB = lds + 8192;
  const int tid = threadIdx.x, lane = tid & 63, wave = tid >> 6;
  const int fr = lane & 15, q = lane >> 4;
  const int m0 = blockIdx.y * 128, n0 = blockIdx.x * 128;
  const int wm = (wave >> 1) * 64, wn = (wave & 1) * 64;
  const int kbase = blockIdx.z * ksteps * 64;

  const ushort_t* Ab = A + (size_t)m0 * K + kbase;
  const ushort_t* Bb = Bw + (size_t)n0 * K + kbase;

  // per-lane staging source base (inst i adds i*8 rows)
  const int kg = (lane & 7) ^ (lane >> 3);
  const ushort_t* gaA = Ab + (size_t)(lane >> 3) * K + kg * 8;
  const ushort_t* gaB = Bb + (size_t)(lane >> 3) * K + kg * 8;

  f32x4 acc[4][4];
  #pragma unroll
  for (int i = 0; i < 4; i++)
    #pragma unroll
    for (int j = 0; j < 4; j++) acc[i][j] = 0.f;

  int rowA[4], rowB[4];
  #pragma unroll
  for (int t = 0; t < 4; t++) {
    rowA[t] = (wm + t * 16 + fr) * 64;
    rowB[t] = (wn + t * 16 + fr) * 64;
  }
  const int sl0 = ((0 * 4 + q) ^ (fr & 7)) * 8;
  const int sl1 = ((1 * 4 + q) ^ (fr & 7)) * 8;

  for (int ks = 0; ks < ksteps; ks++) {
    __syncthreads();
    #pragma unroll
    for (int u = 0; u < 4; u++) {
      const int i = wave * 4 + u;
      gld16(gaA + ks * 64 + (size_t)i * 8 * K, lsA + i * 512);
      gld16(gaB + ks * 64 + (size_t)i * 8 * K, lsB + i * 512);
    }
    __syncthreads();
    #pragma unroll
    for (int s = 0; s < 2; s++) {
      const int sl = s ? sl1 : sl0;
      bf16x8 af[4], bfv[4];
      #pragma unroll
      for (int t = 0; t < 4; t++) {
        af[t]  = *(const bf16x8*)(lsA + rowA[t] + sl);
        bfv[t] = *(const bf16x8*)(lsB + rowB[t] + sl);
      }
      #pragma unroll
      for (int i = 0; i < 4; i++)
        #pragma unroll
        for (int j = 0; j < 4; j++)
          acc[i][j] = __builtin_amdgcn_mfma_f32_16x16x32_bf16(af[i], bfv[j], acc[i][j], 0, 0, 0);
    }
  }

  // C/D layout col=lane&15, row=(lane>>4)*4+reg (m89/m91-verified)
  if (OBF) {
    __syncthreads();                     // staging LDS now dead for all waves
    ushort_t* myl = lds + wave * 2048;   // private 4KB per wave
    const int rloc = lane >> 2, cg = lane & 3;
    #pragma unroll
    for (int hh = 0; hh < 2; hh++) {     // column halves (32 cols each)
      #pragma unroll
      for (int j2 = 0; j2 < 2; j2++) {
        const int j = 2 * hh + j2;
        const float bv = bias ? bias[n0 + wn + j * 16 + fr] : 0.f;
        #pragma unroll
        for (int i = 0; i < 4; i++) {
          #pragma unroll
          for (int rr = 0; rr < 4; rr++) {
            const int row = i * 16 + q * 4 + rr;
            const int col = j2 * 16 + fr;       // 0..31
            float v = acc[i][j][rr] + bv;
            if (RELU) v = fmaxf(v, 0.f);
            const int cgw = col >> 3, cwi = col & 7;
            myl[(row * 4 + (cgw ^ (row & 3) ^ ((row >> 2) & 3))) * 8 + cwi] = f2bf(v);
          }
        }
      }
      #pragma unroll
      for (int rb = 0; rb < 4; rb++) {
        const int row = rb * 16 + rloc;
        const int cgr = cg ^ (row & 3) ^ ((row >> 2) & 3);
        bf16x8 seg = *(const bf16x8*)&myl[(row * 4 + cgr) * 8];
        const size_t gaddr = (size_t)(m0 + wm + row) * N + (n0 + wn + hh * 32 + cg * 8);
        if (RESID) {
          const bf16x8 rv = *(const bf16x8*)&resid[gaddr];
          #pragma unroll
          for (int e = 0; e < 8; e++) {
            const float f = bf2f((ushort_t)seg[e]) + bf2f((ushort_t)rv[e]);
            seg[e] = (short)f2bf(f);
          }
        }
        *(bf16x8*)&outb[gaddr] = seg;
      }
    }
  }
  if (OF32) {  // fp32 split-K partial (final GEMM only; small output)
    float* po = outf + (size_t)blockIdx.z * M * N;
    #pragma unroll
    for (int i = 0; i < 4; i++) {
      const int rb = m0 + wm + i * 16 + q * 4;
      #pragma unroll
      for (int j = 0; j < 4; j++) {
        const int col = n0 + wn + j * 16 + fr;
        #pragma unroll
        for (int rr = 0; rr < 4; rr++)
          po[(size_t)(rb + rr) * N + col] = acc[i][j][rr];
      }
    }
  }
}

// ---------------------------------------------------------------------------
// Fused attention R5: one block per (head, batch). qkv:[BT,3072] bf16.
// K staged in LDS (coalesced); S=Q*K^T in regs; softmax in regs
// (row = fr-lanes x jt-regs within ONE wave; quarter-wave shfl_xor);
// P written bf16 to LDS; ctx = P*V via direct ds_read fragments.
// ---------------------------------------------------------------------------
#define KST 136   // Kls row stride (bf16): 272B rows, 2-way banks (free)
#define VST 120   // Vt row stride (bf16)
#define PST 120   // Pls row stride (bf16)

__global__ __launch_bounds__(256)
void attn_kernel(const ushort_t* __restrict__ qkv, ushort_t* __restrict__ ctx)
{
  __shared__ ushort_t Kls[112 * KST];  // 30464 B
  __shared__ ushort_t Vt[128 * VST];   // 30720 B
  __shared__ ushort_t Pls[64 * PST];   // 15360 B  (total 76544 B -> 2 blk/CU)
  const int tid = threadIdx.x, lane = tid & 63, wave = tid >> 6;
  const int fr = lane & 15, q = lane >> 4;
  const int hh = blockIdx.x, bb = blockIdx.y;
  const size_t base = (size_t)bb * T_ * DQ_;
  const ushort_t* Qb = qkv + base + hh * HD_;
  const ushort_t* Kb = qkv + base + D_ + hh * HD_;
  const ushort_t* Vb = qkv + base + 2 * D_ + hh * HD_;

  // stage K rows 0..99 (16B vector chunks, coalesced)
  for (int e = tid; e < 1600; e += 256) {
    const int j = e >> 4, kc = e & 15;
    *(bf16x8*)&Kls[j * KST + kc * 8] = *(const bf16x8*)(Kb + (size_t)j * DQ_ + kc * 8);
  }
  // zero K pad rows 100..111 (feed masked cols; keep non-NaN)
  for (int e = tid; e < 12 * KST; e += 256) Kls[100 * KST + e] = 0;
  // stage V transposed (Vt[d][key]): 16B vector read, 8-scalar scatter
  for (int e = tid; e < 1600; e += 256) {
    const int j = e >> 4, dc = e & 15;
    const bf16x8 v = *(const bf16x8*)(Vb + (size_t)j * DQ_ + dc * 8);
    #pragma unroll
    for (int u = 0; u < 8; u++) Vt[(dc * 8 + u) * VST + j] = (ushort_t)v[u];
  }
  // zero V pad keys 100..111 (keys 112..127 never read)
  for (int e = tid; e < 128 * 12; e += 256) {
    const int d = e / 12, j = e - d * 12;
    Vt[d * VST + 100 + j] = 0;
  }
  __syncthreads();

  for (int c = 0; c < 2; c++) {
    if (c) __syncthreads();              // Pls reuse across chunks
    // ---- phase 1: S rows of this wave's i-tile, K from LDS ----
    const int it  = c * 4 + wave;
    const bool wlive = (it < 7);
    const int itc = wlive ? it : 6;
    const int qrow = min(itc * 16 + fr, T_ - 1);
    bf16x8 aq[4];
    #pragma unroll
    for (int ks = 0; ks < 4; ks++)
      aq[ks] = *(const bf16x8*)(Qb + (size_t)qrow * DQ_ + ks * 32 + q * 8);
    f32x4 sacc[7];
    #pragma unroll
    for (int jt = 0; jt < 7; jt++) sacc[jt] = 0.f;
    #pragma unroll
    for (int ks = 0; ks < 4; ks++) {
      const int kk = ks * 32 + q * 8;
      #pragma unroll
      for (int jt = 0; jt < 7; jt++) {
        const bf16x8 kb = *(const bf16x8*)&Kls[(jt * 16 + fr) * KST + kk];
        sacc[jt] = __builtin_amdgcn_mfma_f32_16x16x32_bf16(aq[ks], kb, sacc[jt], 0, 0, 0);
      }
    }
    // ---- register softmax: row r=q*4+rr spans fr-lanes x jt-regs ----
    ushort_t pbf[7][4];
    #pragma unroll
    for (int rr = 0; rr < 4; rr++) {
      float sv[7];
      float mx = -1e30f;
      #pragma unroll
      for (int jt = 0; jt < 7; jt++) {
        float s = sacc[jt][rr] * SCALE_;
        if (jt == 6 && fr >= 4) s = -1e30f;   // keys >= 100 masked
        sv[jt] = s;
        mx = fmaxf(mx, s);
      }
      mx = fmaxf(mx, __shfl_xor(mx, 1));
      mx = fmaxf(mx, __shfl_xor(mx, 2));
      mx = fmaxf(mx, __shfl_xor(mx, 4));
      mx = fmaxf(mx, __shfl_xor(mx, 8));
      float sum = 0.f;
      #pragma unroll
      for (int jt = 0; jt < 7; jt++) { sv[jt] = __expf(sv[jt] - mx); sum += sv[jt]; }
      sum += __shfl_xor(sum, 1);
      sum += __shfl_xor(sum, 2);
      sum += __shfl_xor(sum, 4);
      sum += __shfl_xor(sum, 8);
      const float inv = 1.f / sum;
      #pragma unroll
      for (int jt = 0; jt < 7; jt++) pbf[jt][rr] = f2bf(sv[jt] * inv);
    }
    if (wlive) {
      #pragma unroll
      for (int jt = 0; jt < 7; jt++)
        #pragma unroll
        for (int rr = 0; rr < 4; rr++)
          Pls[(wave * 16 + q * 4 + rr) * PST + jt * 16 + fr] = pbf[jt][rr];
    }
    __syncthreads();
    // ---- phase 3: ctx = P*V, fragments straight from LDS ----
    const int mtc = (c == 0) ? 4 : 3;
    f32x4 cacc[4][2];
    #pragma unroll
    for (int i = 0; i < 4; i++) { cacc[i][0] = 0.f; cacc[i][1] = 0.f; }
    #pragma unroll
    for (int ks = 0; ks < 4; ks++) {
      const int kk = ks * 32 + q * 8;
      const bool live = (ks < 3) || (q < 2);   // keys < 112
      bf16x8 v0 = 0, v1 = 0;
      if (live) {
        v0 = *(const bf16x8*)&Vt[((wave * 2 + 0) * 16 + fr) * VST + kk];
        v1 = *(const bf16x8*)&Vt[((wave * 2 + 1) * 16 + fr) * VST + kk];
      }
      for (int mt = 0; mt < mtc; mt++) {
        bf16x8 a = 0;
        if (live) a = *(const bf16x8*)&Pls[(mt * 16 + fr) * PST + kk];
        cacc[mt][0] = __builtin_amdgcn_mfma_f32_16x16x32_bf16(a, v0, cacc[mt][0], 0, 0, 0);
        cacc[mt][1] = __builtin_amdgcn_mfma_f32_16x16x32_bf16(a, v1, cacc[mt][1], 0, 0, 0);
      }
    }
    for (int mt = 0; mt < mtc; mt++) {
      #pragma unroll
      for (int nn = 0; nn < 2; nn++) {
        const int col = hh * HD_ + (wave * 2 + nn) * 16 + fr;
        #pragma unroll
        for (int rr = 0; rr < 4; rr++) {
          const int r = c * 64 + mt * 16 + q * 4 + rr;
          if (r < T_)
            ctx[(size_t)(bb * T_ + r) * D_ + col] = f2bf(cacc[mt][nn][rr]);
        }
      }
    }
  }
}

// ---------------------------------------------------------------------------
// LayerNorm: bf16 in -> bf16 out (fp32 stats). One block per row.
// ---------------------------------------------------------------------------
__global__ __launch_bounds__(256)
void ln_kernel(const ushort_t* __restrict__ in, ushort_t* __restrict__ outb,
               const float* __restrict__ g, const float* __restrict__ bta)
{
  const int row = blockIdx.x, tid = threadIdx.x;
  const int c4 = tid * 4;
  const ushort4 uv = *(const ushort4*)(in + (size_t)row * D_ + c4);
  const float v0 = bf2f(uv.x), v1 = bf2f(uv.y), v2 = bf2f(uv.z), v3 = bf2f(uv.w);
  float s  = v0 + v1 + v2 + v3;
  float ss = v0*v0 + v1*v1 + v2*v2 + v3*v3;
  #pragma unroll
  for (int o = 1; o < 64; o <<= 1) {
    s  += __shfl_xor(s, o);
    ss += __shfl_xor(ss, o);
  }
  __shared__ float red[8];
  const int lane = tid & 63, wave = tid >> 6;
  if (lane == 0) { red[wave] = s; red[4 + wave] = ss; }
  __syncthreads();
  s  = red[0] + red[1] + red[2] + red[3];
  ss = red[4] + red[5] + red[6] + red[7];
  const float mean = s * (1.f / D_);
  const float var  = ss * (1.f / D_) - mean * mean;
  const float rstd = rsqrtf(var + 1e-5f);
  const float4 gv = *(const float4*)(g + c4);
  const float4 bv = *(const float4*)(bta + c4);
  ushort4 ob = { f2bf((v0 - mean) * rstd * gv.x + bv.x),
                 f2bf((v1 - mean) * rstd * gv.y + bv.y),
                 f2bf((v2 - mean) * rstd * gv.z + bv.z),
                 f2bf((v3 - mean) * rstd * gv.w + bv.w) };
  *(ushort4*)(outb + (size_t)row * D_ + c4) = ob;
}

// ---------------------------------------------------------------------------
// Embedding: h = x@Wi + bi + PE(t,:) -> bf16. One block per token row.
// ---------------------------------------------------------------------------
__global__ __launch_bounds__(256)
void embed_kernel(const float* __restrict__ x, const float* __restrict__ Wi,
                  const float* __restrict__ bi, ushort_t* hbf)
{
  const int row = blockIdx.x;
  const int t = row % T_;
  const int c = threadIdx.x * 4;
  float xv[6];
  #pragma unroll
  for (int i = 0; i < 6; i++) xv[i] = x[row * 6 + i];
  ushort4 ob;
  ushort_t* obp = (ushort_t*)&ob;
  #pragma unroll
  for (int u = 0; u < 4; u++) {
    const int d = c + u;
    float a = bi[d];
    #pragma unroll
    for (int i = 0; i < 6; i++) a += xv[i] * Wi[i * D_ + d];
    const int k = d >> 1;
    const float ang = (float)t * expf((float)k * -0.017988946039015984f); // -ln(1e4)/512
    a += (d & 1) ? cosf(ang) : sinf(ang);
    obp[u] = f2bf(a);
  }
  *(ushort4*)(hbf + (size_t)row * D_ + c) = ob;
}

// All weight tensors -> bf16 in one launch.
#define NQW (L_*DQ_*D_)   // 12582912
#define NDW (L_*D_*D_)    //  4194304
__global__ void cvt_all(const float* __restrict__ qw, const float* __restrict__ ow,
                        const float* __restrict__ f1, const float* __restrict__ f2,
                        ushort_t* wq, ushort_t* wo, ushort_t* w1, ushort_t* w2)
{
  const size_t i = ((size_t)blockIdx.x * 256 + threadIdx.x) * 4;
  const float* s; ushort_t* d; size_t off;
  if (i < NQW)                { s = qw; d = wq; off = i; }
  else if (i < NQW + NDW)     { s = ow; d = wo; off = i - NQW; }
  else if (i < NQW + 2*NDW)   { s = f1; d = w1; off = i - NQW - NDW; }
  else                        { s = f2; d = w2; off = i - NQW - 2*NDW; }
  const float4 v = *(const float4*)(s + off);
  ushort4 o = { f2bf(v.x), f2bf(v.y), f2bf(v.z), f2bf(v.w) };
  *(ushort4*)(d + off) = o;
}

// Wo [KFIN,256] fp32 -> Wot [256,KFIN] bf16
__global__ __launch_bounds__(256)
void transpose_wo(const float* __restrict__ src, ushort_t* __restrict__ dst)
{
  __shared__ float tile[64][65];
  const int k0 = blockIdx.x * 64, n0 = blockIdx.y * 64;
  const int tc = threadIdx.x & 63, tr = threadIdx.x >> 6;
  #pragma unroll
  for (int i = 0; i < 16; i++) {
    const int r = i * 4 + tr;
    tile[r][tc] = src[(size_t)(k0 + r) * OUT_ + n0 + tc];
  }
  __syncthreads();
  #pragma unroll
  for (int i = 0; i < 16; i++) {
    const int n = i * 4 + tr;
    dst[(size_t)(n0 + n) * KFIN_ + k0 + tc] = f2bf(tile[tc][n]);
  }
}

__global__ void reduce_final(const float* __restrict__ part,
                             const float* __restrict__ bo, float* __restrict__ out)
{
  const int i = blockIdx.x * 256 + threadIdx.x;   // 65536 outputs
  float s = bo[i & (OUT_ - 1)];
  for (int z = 0; z < KSPLIT_; z++) s += part[(size_t)z * OUT_ * OUT_ + i];
  out[i] = s;
}

// ---------------------------------------------------------------------------
extern "C" void kernel_launch(void* const* d_in, const int* in_sizes, int n_in,
                              void* d_out, int out_size, void* d_ws, size_t ws_size,
                              hipStream_t stream)
{
  (void)in_sizes; (void)n_in; (void)out_size; (void)ws_size;
  const float* x     = (const float*)d_in[0];
  const float* Wi    = (const float*)d_in[1];
  const float* bi    = (const float*)d_in[2];
  const float* qkv_w = (const float*)d_in[3];
  const float* qkv_b = (const float*)d_in[4];
  const float* out_w = (const float*)d_in[5];
  const float* out_b = (const float*)d_in[6];
  const float* ff1_w = (const float*)d_in[7];
  const float* ff1_b = (const float*)d_in[8];
  const float* ff2_w = (const float*)d_in[9];
  const float* ff2_b = (const float*)d_in[10];
  const float* ln1_g = (const float*)d_in[11];
  const float* ln1_b = (const float*)d_in[12];
  const float* ln2_g = (const float*)d_in[13];
  const float* ln2_b = (const float*)d_in[14];
  const float* Wo    = (const float*)d_in[15];
  const float* bo    = (const float*)d_in[16];
  float* out = (float*)d_out;

  // workspace layout — 312 MiB peak
  char* p = (char*)d_ws;
  ushort_t* hbf  = (ushort_t*)p; p += (size_t)BT_ * D_ * 2;     //  52.4 MB
  ushort_t* qkvb = (ushort_t*)p; p += (size_t)BT_ * DQ_ * 2;    // 157.3 MB
  ushort_t* ctxb = (ushort_t*)p; p += (size_t)BT_ * D_ * 2;     //  52.4 MB
  ushort_t* wq   = (ushort_t*)p; p += (size_t)NQW * 2;          //  25.2 MB
  ushort_t* wo   = (ushort_t*)p; p += (size_t)NDW * 2;          //   8.4 MB
  ushort_t* w1   = (ushort_t*)p; p += (size_t)NDW * 2;          //   8.4 MB
  ushort_t* w2   = (ushort_t*)p; p += (size_t)NDW * 2;          //   8.4 MB
  ushort_t* ffact = qkvb;                         // qkv dead after attention
  ushort_t* sum   = qkvb + (size_t)BT_ * D_;      // pre-LN sum (slot 1)
  ushort_t* wot   = ctxb;                         // ctx dead after last out-proj
  float*    part  = (float*)qkvb;                 // final split-K partials

  cvt_all<<<dim3((NQW + 3*NDW) / 1024), 256, 0, stream>>>(
      qkv_w, out_w, ff1_w, ff2_w, wq, wo, w1, w2);
  embed_kernel<<<dim3(BT_), 256, 0, stream>>>(x, Wi, bi, hbf);

  for (int i = 0; i < L_; i++) {
    // qkv = h @ qkv_w^T + b  -> bf16
    gemm_nt<0,0,1,0><<<dim3(DQ_/128, BT_/128, 1), 256, 0, stream>>>(
        hbf, wq + (size_t)i * DQ_ * D_, qkv_b + i * DQ_,
        qkvb, nullptr, nullptr, BT_, DQ_, D_, D_ / 64);
    attn_kernel<<<dim3(H_, B_), 256, 0, stream>>>(qkvb, ctxb);
    // sum = ctx @ out_w^T + b + h   (bf16)
    gemm_nt<0,1,1,0><<<dim3(D_/128, BT_/128, 1), 256, 0, stream>>>(
        ctxb, wo + (size_t)i * D_ * D_, out_b + i * D_,
        sum, nullptr, hbf, BT_, D_, D_, D_ / 64);
    ln_kernel<<<dim3(BT_), 256, 0, stream>>>(sum, hbf, ln1_g + i * D_, ln1_b + i * D_);
    // ff = relu(h @ ff1^T + b) -> bf16
    gemm_nt<1,0,1,0><<<dim3(D_/128, BT_/128, 1), 256, 0, stream>>>(
        hbf, w1 + (size_t)i * D_ * D_, ff1_b + i * D_,
        ffact, nullptr, nullptr, BT_, D_, D_, D_ / 64);
    // sum = ff @ ff2^T + b + h   (bf16)
    gemm_nt<0,1,1,0><<<dim3(D_/128, BT_/128, 1), 256, 0, stream>>>(
        ffact, w2 + (size_t)i * D_ * D_, ff2_b + i * D_,
        sum, nullptr, hbf, BT_, D_, D_, D_ / 64);
    ln_kernel<<<dim3(BT_), 256, 0, stream>>>(sum, hbf, ln2_g + i * D_, ln2_b + i * D_);
  }

  // final: out = h.reshape(256,102400) @ Wo + bo   (split-K partials + reduce)
  transpose_wo<<<dim3(KFIN_/64, OUT_/64), 256, 0, stream>>>(Wo, wot);
  gemm_nt<0,0,0,1><<<dim3(OUT_/128, OUT_/128, KSPLIT_), 256, 0, stream>>>(
      hbf, wot, nullptr, nullptr, part, nullptr,
      OUT_, OUT_, KFIN_, KFIN_ / (KSPLIT_ * 64));
  reduce_final<<<dim3(OUT_ * OUT_ / 256), 256, 0, stream>>>(part, bo, out);
}